// Round 1
// baseline (7205.479 us; speedup 1.0000x reference)
//
#include <hip/hip_runtime.h>
#include <hip/hip_bf16.h>

typedef __hip_bfloat16 bf16;
typedef __attribute__((ext_vector_type(8))) __bf16 bf16x8;
typedef __attribute__((ext_vector_type(4))) float f32x4;

// ---------------------------------------------------------------- constants
// D=768, H=12, DH=64, L=12, FF=3072, P=16, IMG=224, NPR=8, B=64, S=205
static constexpr int B_   = 64;
static constexpr int S_   = 205;          // tokens per image (197 + 8 prompts)
static constexpr int D_   = 768;
static constexpr int FF_  = 3072;
static constexpr int L_   = 12;
static constexpr int MTOK = B_ * S_;      // 13120
static constexpr int MPAD = 13184;        // 103 * 128
static constexpr int MP_  = 12544;        // 64*196 patch rows = 98*128

// workspace layout (bytes, each section naturally 256-aligned)
static constexpr size_t OFF_QKVW = 0;                                          // [12][2304][768] bf16
static constexpr size_t OFF_OW   = OFF_QKVW + (size_t)12*2304*768*2;           // [12][768][768] bf16
static constexpr size_t OFF_FC1W = OFF_OW   + (size_t)12*768*768*2;            // [12][3072][768] bf16
static constexpr size_t OFF_FC2W = OFF_FC1W + (size_t)12*3072*768*2;           // [12][768][3072] bf16
static constexpr size_t OFF_PW   = OFF_FC2W + (size_t)12*768*3072*2;           // [768][768] bf16
static constexpr size_t OFF_QKVB = OFF_PW   + (size_t)768*768*2;               // [12][2304] f32
static constexpr size_t OFF_X    = OFF_QKVB + (size_t)12*2304*4;               // [13184][768] f32 residual stream
static constexpr size_t OFF_H    = OFF_X    + (size_t)MPAD*768*4;              // [13184][768] bf16 (also im2col [12544][768])
static constexpr size_t OFF_QKV  = OFF_H    + (size_t)MPAD*768*2;              // [13184][2304] bf16
static constexpr size_t OFF_FF   = OFF_QKV  + (size_t)MPAD*2304*2;             // [13184][3072] bf16 (also feat f32 [12544][768])
// total = OFF_FF + 13184*3072*2  ~= 374 MB

// ---------------------------------------------------------------- helpers
__device__ __forceinline__ f32x4 mfma16(bf16x8 a, bf16x8 b, f32x4 c) {
  return __builtin_amdgcn_mfma_f32_16x16x32_bf16(a, b, c, 0, 0, 0);
}

__device__ __forceinline__ void async_ld16(const bf16* g, bf16* l) {
  __builtin_amdgcn_global_load_lds(
      (const __attribute__((address_space(1))) unsigned int*)g,
      (__attribute__((address_space(3))) unsigned int*)l, 16, 0, 0);
}

// ---------------------------------------------------------------- converts
__global__ __launch_bounds__(256) void cvt_bf16_kernel(const float* __restrict__ src,
                                                       bf16* __restrict__ dst, int n4) {
  int i = blockIdx.x * 256 + threadIdx.x;
  if (i >= n4) return;
  float4 v = ((const float4*)src)[i];
  int e = i * 4;
  dst[e + 0] = __float2bfloat16(v.x);
  dst[e + 1] = __float2bfloat16(v.y);
  dst[e + 2] = __float2bfloat16(v.z);
  dst[e + 3] = __float2bfloat16(v.w);
}

__global__ __launch_bounds__(256) void cvt_qkvw_kernel(const float* __restrict__ qw,
    const float* __restrict__ kw, const float* __restrict__ vw, bf16* __restrict__ dst) {
  int i = blockIdx.x * 256 + threadIdx.x;
  const int total = 12 * 2304 * 768 / 4;
  if (i >= total) return;
  int e = i * 4;
  int l = e / (2304 * 768);
  int r = e - l * (2304 * 768);
  int o = r / 768;
  int d = r - o * 768;
  const float* src;
  if (o < 768)       src = qw + ((size_t)l * 768 + o) * 768 + d;
  else if (o < 1536) src = kw + ((size_t)l * 768 + (o - 768)) * 768 + d;
  else               src = vw + ((size_t)l * 768 + (o - 1536)) * 768 + d;
  float4 v = *(const float4*)src;
  dst[e + 0] = __float2bfloat16(v.x);
  dst[e + 1] = __float2bfloat16(v.y);
  dst[e + 2] = __float2bfloat16(v.z);
  dst[e + 3] = __float2bfloat16(v.w);
}

__global__ __launch_bounds__(256) void cvt_qkvb_kernel(const float* __restrict__ qb,
    const float* __restrict__ kb, const float* __restrict__ vb, float* __restrict__ dst) {
  int i = blockIdx.x * 256 + threadIdx.x;
  if (i >= 12 * 2304) return;
  int l = i / 2304, o = i - l * 2304;
  float v = (o < 768) ? qb[l * 768 + o] : (o < 1536) ? kb[l * 768 + o - 768] : vb[l * 768 + o - 1536];
  dst[i] = v;
}

// ---------------------------------------------------------------- patch embed
__global__ __launch_bounds__(256) void im2col_kernel(const float* __restrict__ img,
                                                     bf16* __restrict__ dst) {
  int idx = blockIdx.x * 256 + threadIdx.x;
  if (idx >= MP_ * 768) return;
  int k = idx % 768;
  int m = idx / 768;
  int b = m / 196, p = m - b * 196;
  int py = p / 14, px = p - py * 14;
  int c = k >> 8, rr = k & 255, kh = rr >> 4, kw_ = rr & 15;
  dst[idx] = __float2bfloat16(img[((size_t)(b * 3 + c) * 224 + py * 16 + kh) * 224 + px * 16 + kw_]);
}

__global__ __launch_bounds__(256) void assemble_kernel(const float* __restrict__ feat,
    const float* __restrict__ cls, const float* __restrict__ pos,
    const float* __restrict__ gp, float* __restrict__ x) {
  int idx = blockIdx.x * 256 + threadIdx.x;
  if (idx >= MTOK * 768) return;
  int d = idx % 768;
  int t = idx / 768;
  int s = t % 205;
  int b = t / 205;
  float v;
  if (s == 0)        v = cls[d] + pos[d];
  else if (s < 197)  v = feat[((size_t)b * 196 + (s - 1)) * 768 + d] + pos[(size_t)s * 768 + d];
  else               v = gp[(((size_t)b * 12 + 0) * 8 + (s - 197)) * 768 + d];
  x[idx] = v;
}

__global__ __launch_bounds__(256) void prompt_replace_kernel(const float* __restrict__ gp,
                                                             float* __restrict__ x, int layer) {
  int idx = blockIdx.x * 256 + threadIdx.x;
  if (idx >= B_ * 8 * 768) return;
  int d = idx % 768;
  int t = idx / 768;
  int j = t & 7, b = t >> 3;
  x[((size_t)(b * 205 + 197 + j)) * 768 + d] = gp[(((size_t)b * 12 + layer) * 8 + j) * 768 + d];
}

// ---------------------------------------------------------------- layernorm (1 wave / row, fp32)
__global__ __launch_bounds__(256) void ln_kernel(const float* __restrict__ x, int irs,
    const float* __restrict__ g, const float* __restrict__ be,
    void* __restrict__ out, int ors, int out_bf16, int nrows) {
  int row = blockIdx.x * 4 + (threadIdx.x >> 6);
  if (row >= nrows) return;
  int lane = threadIdx.x & 63;
  const float* xr = x + (size_t)row * irs;
  float v[12];
  float s = 0.f;
#pragma unroll
  for (int i = 0; i < 12; ++i) { v[i] = xr[lane + 64 * i]; s += v[i]; }
#pragma unroll
  for (int m = 1; m < 64; m <<= 1) s += __shfl_xor(s, m, 64);
  float mu = s * (1.f / 768.f);
  float ss = 0.f;
#pragma unroll
  for (int i = 0; i < 12; ++i) { float dd = v[i] - mu; ss += dd * dd; }
#pragma unroll
  for (int m = 1; m < 64; m <<= 1) ss += __shfl_xor(ss, m, 64);
  float rstd = rsqrtf(ss * (1.f / 768.f) + 1e-5f);
#pragma unroll
  for (int i = 0; i < 12; ++i) {
    int d = lane + 64 * i;
    float o = (v[i] - mu) * rstd * g[d] + be[d];
    if (out_bf16) ((bf16*)out)[(size_t)row * ors + d] = __float2bfloat16(o);
    else          ((float*)out)[(size_t)row * ors + d] = o;
  }
}

// ---------------------------------------------------------------- GEMM: out[m,n] = act((A[m,:] . W[n,:] + bias[n]) * sc) + residual
// A: bf16 [Mpad][lda], W: bf16 [N][ldw]. 128x128x32 tiles, global_load_lds staging,
// 16x16x32 bf16 MFMA. Verified layouts: A/B frag row=lane&15, k=quad*8+j; C col=lane&15, row=quad*4+reg.
__global__ __launch_bounds__(256) void gemm_kernel(
    const bf16* __restrict__ A, int lda,
    const bf16* __restrict__ W, int ldw,
    const float* __restrict__ bias,
    void* __restrict__ out, int ldo, int out_bf16,
    const float* __restrict__ residual, int ldr,
    int act, float scale, int scale_limit,
    int M_valid, int K) {
  __shared__ __align__(16) bf16 As[128 * 32];
  __shared__ __align__(16) bf16 Bs[128 * 32];
  const int tid = threadIdx.x;
  const int wave = tid >> 6, lane = tid & 63;
  const int quad = lane >> 4, l16 = lane & 15;
  const int m0 = blockIdx.x * 128, n0 = blockIdx.y * 128;
  const int wm = (wave & 1) * 64, wn = (wave >> 1) * 64;

  const bf16* a_src = A + (size_t)(m0 + (tid >> 2)) * lda + (tid & 3) * 8;
  const bf16* b_src = W + (size_t)(n0 + (tid >> 2)) * ldw + (tid & 3) * 8;
  bf16* As_w0 = As + (wave * 16) * 32;
  bf16* As_w1 = As + (64 + wave * 16) * 32;
  bf16* Bs_w0 = Bs + (wave * 16) * 32;
  bf16* Bs_w1 = Bs + (64 + wave * 16) * 32;
  const size_t a_step = (size_t)64 * lda;
  const size_t b_step = (size_t)64 * ldw;

  f32x4 acc[4][4];
#pragma unroll
  for (int tm = 0; tm < 4; ++tm)
#pragma unroll
    for (int tn = 0; tn < 4; ++tn) {
      f32x4 z = {0.f, 0.f, 0.f, 0.f};
      acc[tm][tn] = z;
    }

  for (int k0 = 0; k0 < K; k0 += 32) {
    async_ld16(a_src + k0, As_w0);
    async_ld16(a_src + a_step + k0, As_w1);
    async_ld16(b_src + k0, Bs_w0);
    async_ld16(b_src + b_step + k0, Bs_w1);
    __syncthreads();   // drains vmcnt(0) incl. global_load_lds
    bf16x8 af[4], bfr[4];
#pragma unroll
    for (int tm = 0; tm < 4; ++tm)
      af[tm] = *(const bf16x8*)(As + (wm + tm * 16 + l16) * 32 + quad * 8);
#pragma unroll
    for (int tn = 0; tn < 4; ++tn)
      bfr[tn] = *(const bf16x8*)(Bs + (wn + tn * 16 + l16) * 32 + quad * 8);
#pragma unroll
    for (int tm = 0; tm < 4; ++tm)
#pragma unroll
      for (int tn = 0; tn < 4; ++tn)
        acc[tm][tn] = mfma16(af[tm], bfr[tn], acc[tm][tn]);
    __syncthreads();
  }

#pragma unroll
  for (int tm = 0; tm < 4; ++tm) {
#pragma unroll
    for (int tn = 0; tn < 4; ++tn) {
      const int col = n0 + wn + tn * 16 + l16;
      const float bv = bias ? bias[col] : 0.f;
      const float sc = (col < scale_limit) ? scale : 1.f;
#pragma unroll
      for (int r = 0; r < 4; ++r) {
        const int row = m0 + wm + tm * 16 + quad * 4 + r;
        if (row < M_valid) {
          float v = (acc[tm][tn][r] + bv) * sc;
          if (residual) v += residual[(size_t)row * ldr + col];
          if (act) v = v / (1.f + __expf(-1.702f * v));   // QuickGELU
          if (out_bf16) ((bf16*)out)[(size_t)row * ldo + col] = __float2bfloat16(v);
          else          ((float*)out)[(size_t)row * ldo + col] = v;
        }
      }
    }
  }
}

// ---------------------------------------------------------------- fused attention: one block per (b,h)
// qkv: bf16 [MPAD][2304]; q pre-scaled by 0.125 with bias. out: bf16 [MPAD][768].
// LDS: K [208][72], V^T [64][232] (keys padded to 224 with zeros), per-wave P chunk [16][40].
__global__ __launch_bounds__(256) void attn_kernel(const bf16* __restrict__ qkv,
                                                   bf16* __restrict__ outb) {
  __shared__ __align__(16) bf16 Ks[208 * 72];
  __shared__ __align__(16) bf16 Vt[64 * 232];
  __shared__ __align__(16) bf16 Pc[4 * 16 * 40];
  const int h = blockIdx.x, b = blockIdx.y;
  const int tid = threadIdx.x;
  const int wave = tid >> 6, lane = tid & 63, quad = lane >> 4, l16 = lane & 15;
  const size_t rowbase = (size_t)b * 205;

  // stage K rows 0..207 (rows >=205 zeroed)
  for (int idx = tid; idx < 208 * 8; idx += 256) {
    int s = idx >> 3, c = idx & 7;
    uint4 val = {0u, 0u, 0u, 0u};
    if (s < 205) val = *(const uint4*)(qkv + (rowbase + s) * 2304 + 768 + h * 64 + c * 8);
    *(uint4*)(Ks + s * 72 + c * 8) = val;
  }
  // stage V transposed, key cols 0..223 (>=205 zeroed)
  for (int idx = tid; idx < 224 * 8; idx += 256) {
    int s = idx >> 3, c = idx & 7;
    bf16 tmp[8];
    if (s < 205) {
      *(uint4*)tmp = *(const uint4*)(qkv + (rowbase + s) * 2304 + 1536 + h * 64 + c * 8);
    } else {
#pragma unroll
      for (int j = 0; j < 8; ++j) tmp[j] = __float2bfloat16(0.f);
    }
#pragma unroll
    for (int j = 0; j < 8; ++j) Vt[(c * 8 + j) * 232 + s] = tmp[j];
  }
  __syncthreads();

  bf16* Pm = Pc + wave * (16 * 40);

  for (int t = 0; t < 4; ++t) {
    const int it = t * 4 + wave;     // query i-tile (16 rows); 13 tiles total
    if (it >= 13) continue;          // no barriers below -> divergence safe
    const int row0 = it * 16;
    const bf16* qr = qkv + (rowbase + row0 + l16) * 2304 + h * 64;
    bf16x8 qf0 = *(const bf16x8*)(qr + quad * 8);
    bf16x8 qf1 = *(const bf16x8*)(qr + 32 + quad * 8);

    f32x4 sc[13];
#pragma unroll
    for (int nt = 0; nt < 13; ++nt) {
      f32x4 a = {0.f, 0.f, 0.f, 0.f};
      const bf16* kr = Ks + (nt * 16 + l16) * 72 + quad * 8;
      a = mfma16(qf0, *(const bf16x8*)kr, a);
      a = mfma16(qf1, *(const bf16x8*)(kr + 32), a);
      sc[nt] = a;
    }
    if (l16 >= 13) {   // keys 205..207 invalid (only in tile 12)
#pragma unroll
      for (int r = 0; r < 4; ++r) sc[12][r] = -1e30f;
    }

    float inv[4];
#pragma unroll
    for (int r = 0; r < 4; ++r) {    // row = quad*4 + r; reduce over 16 col-lanes
      float m = sc[0][r];
#pragma unroll
      for (int nt = 1; nt < 13; ++nt) m = fmaxf(m, sc[nt][r]);
      m = fmaxf(m, __shfl_xor(m, 1, 64));
      m = fmaxf(m, __shfl_xor(m, 2, 64));
      m = fmaxf(m, __shfl_xor(m, 4, 64));
      m = fmaxf(m, __shfl_xor(m, 8, 64));
      float su = 0.f;
#pragma unroll
      for (int nt = 0; nt < 13; ++nt) { float e = __expf(sc[nt][r] - m); sc[nt][r] = e; su += e; }
      su += __shfl_xor(su, 1, 64);
      su += __shfl_xor(su, 2, 64);
      su += __shfl_xor(su, 4, 64);
      su += __shfl_xor(su, 8, 64);
      inv[r] = 1.f / su;
    }

    f32x4 o0 = {0.f,0.f,0.f,0.f}, o1 = {0.f,0.f,0.f,0.f}, o2 = {0.f,0.f,0.f,0.f}, o3 = {0.f,0.f,0.f,0.f};
#pragma unroll
    for (int ks = 0; ks < 7; ++ks) {       // 32 keys per chunk, 224 padded
      // C-layout -> A-layout via per-wave LDS chunk
#pragma unroll
      for (int half = 0; half < 2; ++half) {
        const int nt = ks * 2 + half;
#pragma unroll
        for (int r = 0; r < 4; ++r) {
          float pv = (nt < 13) ? sc[nt][r] * inv[r] : 0.f;
          Pm[(quad * 4 + r) * 40 + half * 16 + l16] = __float2bfloat16(pv);
        }
      }
      asm volatile("s_waitcnt lgkmcnt(0)" ::: "memory");
      bf16x8 pf = *(const bf16x8*)(Pm + l16 * 40 + quad * 8);
      const bf16* vb_ = Vt + l16 * 232 + ks * 32 + quad * 8;
      o0 = mfma16(pf, *(const bf16x8*)(vb_ + 0 * 16 * 232), o0);
      o1 = mfma16(pf, *(const bf16x8*)(vb_ + 1 * 16 * 232), o1);
      o2 = mfma16(pf, *(const bf16x8*)(vb_ + 2 * 16 * 232), o2);
      o3 = mfma16(pf, *(const bf16x8*)(vb_ + 3 * 16 * 232), o3);
      asm volatile("s_waitcnt lgkmcnt(0)" ::: "memory");
    }
#pragma unroll
    for (int r = 0; r < 4; ++r) {
      const int s = row0 + quad * 4 + r;
      if (s < 205) {
        bf16* op = outb + (rowbase + s) * 768 + h * 64 + l16;
        op[0]  = __float2bfloat16(o0[r]);
        op[16] = __float2bfloat16(o1[r]);
        op[32] = __float2bfloat16(o2[r]);
        op[48] = __float2bfloat16(o3[r]);
      }
    }
  }
}

// ---------------------------------------------------------------- launcher
extern "C" void kernel_launch(void* const* d_in, const int* in_sizes, int n_in,
                              void* d_out, int out_size, void* d_ws, size_t ws_size,
                              hipStream_t stream) {
  const float* image  = (const float*)d_in[0];
  const float* gp     = (const float*)d_in[1];
  const float* patchw = (const float*)d_in[2];
  const float* clse   = (const float*)d_in[3];
  const float* pose   = (const float*)d_in[4];
  const float* pre_g  = (const float*)d_in[5];
  const float* pre_b  = (const float*)d_in[6];
  const float* ln1_g  = (const float*)d_in[7];
  const float* ln1_b  = (const float*)d_in[8];
  const float* qw     = (const float*)d_in[9];
  const float* qb     = (const float*)d_in[10];
  const float* kw     = (const float*)d_in[11];
  const float* kb     = (const float*)d_in[12];
  const float* vw     = (const float*)d_in[13];
  const float* vb     = (const float*)d_in[14];
  const float* ow     = (const float*)d_in[15];
  const float* ob     = (const float*)d_in[16];
  const float* ln2_g  = (const float*)d_in[17];
  const float* ln2_b  = (const float*)d_in[18];
  const float* fc1w   = (const float*)d_in[19];
  const float* fc1b   = (const float*)d_in[20];
  const float* fc2w   = (const float*)d_in[21];
  const float* fc2b   = (const float*)d_in[22];
  const float* postg  = (const float*)d_in[23];
  const float* postb  = (const float*)d_in[24];

  char* ws = (char*)d_ws;
  bf16*  qkvw   = (bf16*)(ws + OFF_QKVW);
  bf16*  oww    = (bf16*)(ws + OFF_OW);
  bf16*  fc1wb  = (bf16*)(ws + OFF_FC1W);
  bf16*  fc2wb  = (bf16*)(ws + OFF_FC2W);
  bf16*  pwb    = (bf16*)(ws + OFF_PW);
  float* qkvbias= (float*)(ws + OFF_QKVB);
  float* x      = (float*)(ws + OFF_X);
  bf16*  h      = (bf16*)(ws + OFF_H);     // LN out / attn out / im2col
  bf16*  qkvbuf = (bf16*)(ws + OFF_QKV);
  bf16*  ffbuf  = (bf16*)(ws + OFF_FF);    // FC1 out (bf16) / patch feat (f32)
  float* feat   = (float*)(ws + OFF_FF);

  // --- weight conversion (must run every call: harness re-poisons ws) ---
  cvt_qkvw_kernel<<<20736, 256, 0, stream>>>(qw, kw, vw, qkvw);
  cvt_bf16_kernel<<<6912, 256, 0, stream>>>(ow, oww, 12 * 768 * 768 / 4);
  cvt_bf16_kernel<<<27648, 256, 0, stream>>>(fc1w, fc1wb, 12 * 3072 * 768 / 4);
  cvt_bf16_kernel<<<27648, 256, 0, stream>>>(fc2w, fc2wb, 12 * 768 * 3072 / 4);
  cvt_bf16_kernel<<<576, 256, 0, stream>>>(patchw, pwb, 768 * 768 / 4);
  cvt_qkvb_kernel<<<108, 256, 0, stream>>>(qb, kb, vb, qkvbias);

  // --- patch embedding: im2col + GEMM (no bias) -> feat f32 [12544][768] ---
  im2col_kernel<<<37632, 256, 0, stream>>>(image, h);
  gemm_kernel<<<dim3(98, 6), 256, 0, stream>>>(h, 768, pwb, 768, nullptr,
      feat, 768, 0, nullptr, 0, 0, 1.f, 0, MP_, 768);
  // assemble x = [CLS+pos | feat+pos | prompts(layer0)] then pre-LN (in place, f32)
  assemble_kernel<<<39360, 256, 0, stream>>>(feat, clse, pose, gp, x);
  ln_kernel<<<3280, 256, 0, stream>>>(x, 768, pre_g, pre_b, x, 768, 0, MTOK);

  for (int i = 0; i < L_; ++i) {
    if (i > 0)
      prompt_replace_kernel<<<1536, 256, 0, stream>>>(gp, x, i);
    // LN1 -> h (bf16)
    ln_kernel<<<3280, 256, 0, stream>>>(x, 768, ln1_g + i * 768, ln1_b + i * 768, h, 768, 1, MTOK);
    // fused QKV (q scaled by 0.125 after bias: cols < 768)
    gemm_kernel<<<dim3(103, 18), 256, 0, stream>>>(h, 768,
        qkvw + (size_t)i * 2304 * 768, 768, qkvbias + i * 2304,
        qkvbuf, 2304, 1, nullptr, 0, 0, 0.125f, 768, MTOK, 768);
    // attention -> h (bf16)
    attn_kernel<<<dim3(12, 64), 256, 0, stream>>>(qkvbuf, h);
    // O-proj + residual -> x (f32)
    gemm_kernel<<<dim3(103, 6), 256, 0, stream>>>(h, 768,
        oww + (size_t)i * 768 * 768, 768, ob + i * 768,
        x, 768, 0, x, 768, 0, 1.f, 0, MTOK, 768);
    // LN2 -> h
    ln_kernel<<<3280, 256, 0, stream>>>(x, 768, ln2_g + i * 768, ln2_b + i * 768, h, 768, 1, MTOK);
    // FC1 + QuickGELU -> ffbuf (bf16)
    gemm_kernel<<<dim3(103, 24), 256, 0, stream>>>(h, 768,
        fc1wb + (size_t)i * 3072 * 768, 768, fc1b + i * 3072,
        ffbuf, 3072, 1, nullptr, 0, 1, 1.f, 0, MTOK, 768);
    // FC2 + residual -> x (f32)
    gemm_kernel<<<dim3(103, 6), 256, 0, stream>>>(ffbuf, 3072,
        fc2wb + (size_t)i * 768 * 3072, 3072, fc2b + i * 768,
        x, 768, 0, x, 768, 0, 1.f, 0, MTOK, 3072);
  }

  // final LN on CLS rows -> d_out f32 [64][768]
  ln_kernel<<<16, 256, 0, stream>>>(x, 205 * 768, postg, postb, (float*)d_out, 768, 0, 64);
}

// Round 2
// 5825.466 us; speedup vs baseline: 1.2369x; 1.2369x over previous
//
#include <hip/hip_runtime.h>
#include <hip/hip_bf16.h>

typedef __hip_bfloat16 bf16;
typedef __attribute__((ext_vector_type(8))) __bf16 bf16x8;
typedef __attribute__((ext_vector_type(4))) float f32x4;

// ---------------------------------------------------------------- constants
static constexpr int B_   = 64;
static constexpr int S_   = 205;
static constexpr int D_   = 768;
static constexpr int FF_  = 3072;
static constexpr int L_   = 12;
static constexpr int MTOK = B_ * S_;      // 13120
static constexpr int MPAD = 13184;        // 103 * 128
static constexpr int MP_  = 12544;        // 64*196 patch rows = 98*128

// workspace layout (bytes)
static constexpr size_t OFF_QKVW = 0;                                          // [12][2304][768] bf16
static constexpr size_t OFF_OW   = OFF_QKVW + (size_t)12*2304*768*2;           // [12][768][768] bf16
static constexpr size_t OFF_FC1W = OFF_OW   + (size_t)12*768*768*2;            // [12][3072][768] bf16
static constexpr size_t OFF_FC2W = OFF_FC1W + (size_t)12*3072*768*2;           // [12][768][3072] bf16
static constexpr size_t OFF_PW   = OFF_FC2W + (size_t)12*768*3072*2;           // [768][768] bf16
static constexpr size_t OFF_QKVB = OFF_PW   + (size_t)768*768*2;               // [12][2304] f32
static constexpr size_t OFF_X    = OFF_QKVB + (size_t)12*2304*4;               // [13184][768] f32 residual
static constexpr size_t OFF_H    = OFF_X    + (size_t)MPAD*768*4;              // [13184][768] bf16 / im2col
static constexpr size_t OFF_QKV  = OFF_H    + (size_t)MPAD*768*2;              // [13184][2304] bf16
static constexpr size_t OFF_FF   = OFF_QKV  + (size_t)MPAD*2304*2;             // [13184][3072] bf16 / feat f32

// ---------------------------------------------------------------- helpers
__device__ __forceinline__ f32x4 mfma16(bf16x8 a, bf16x8 b, f32x4 c) {
  return __builtin_amdgcn_mfma_f32_16x16x32_bf16(a, b, c, 0, 0, 0);
}

__device__ __forceinline__ void async_ld16(const bf16* g, bf16* l) {
  __builtin_amdgcn_global_load_lds(
      (const __attribute__((address_space(1))) unsigned int*)g,
      (__attribute__((address_space(3))) unsigned int*)l, 16, 0, 0);
}

// ---------------------------------------------------------------- converts
__global__ __launch_bounds__(256) void cvt_bf16_kernel(const float* __restrict__ src,
                                                       bf16* __restrict__ dst, int n4) {
  int i = blockIdx.x * 256 + threadIdx.x;
  if (i >= n4) return;
  float4 v = ((const float4*)src)[i];
  int e = i * 4;
  dst[e + 0] = __float2bfloat16(v.x);
  dst[e + 1] = __float2bfloat16(v.y);
  dst[e + 2] = __float2bfloat16(v.z);
  dst[e + 3] = __float2bfloat16(v.w);
}

__global__ __launch_bounds__(256) void cvt_qkvw_kernel(const float* __restrict__ qw,
    const float* __restrict__ kw, const float* __restrict__ vw, bf16* __restrict__ dst) {
  int i = blockIdx.x * 256 + threadIdx.x;
  const int total = 12 * 2304 * 768 / 4;
  if (i >= total) return;
  int e = i * 4;
  int l = e / (2304 * 768);
  int r = e - l * (2304 * 768);
  int o = r / 768;
  int d = r - o * 768;
  const float* src;
  if (o < 768)       src = qw + ((size_t)l * 768 + o) * 768 + d;
  else if (o < 1536) src = kw + ((size_t)l * 768 + (o - 768)) * 768 + d;
  else               src = vw + ((size_t)l * 768 + (o - 1536)) * 768 + d;
  float4 v = *(const float4*)src;
  dst[e + 0] = __float2bfloat16(v.x);
  dst[e + 1] = __float2bfloat16(v.y);
  dst[e + 2] = __float2bfloat16(v.z);
  dst[e + 3] = __float2bfloat16(v.w);
}

__global__ __launch_bounds__(256) void cvt_qkvb_kernel(const float* __restrict__ qb,
    const float* __restrict__ kb, const float* __restrict__ vb, float* __restrict__ dst) {
  int i = blockIdx.x * 256 + threadIdx.x;
  if (i >= 12 * 2304) return;
  int l = i / 2304, o = i - l * 2304;
  float v = (o < 768) ? qb[l * 768 + o] : (o < 1536) ? kb[l * 768 + o - 768] : vb[l * 768 + o - 1536];
  dst[i] = v;
}

// ---------------------------------------------------------------- patch embed
__global__ __launch_bounds__(256) void im2col_kernel(const float* __restrict__ img,
                                                     bf16* __restrict__ dst) {
  int idx = blockIdx.x * 256 + threadIdx.x;
  if (idx >= MP_ * 768) return;
  int k = idx % 768;
  int m = idx / 768;
  int b = m / 196, p = m - b * 196;
  int py = p / 14, px = p - py * 14;
  int c = k >> 8, rr = k & 255, kh = rr >> 4, kw_ = rr & 15;
  dst[idx] = __float2bfloat16(img[((size_t)(b * 3 + c) * 224 + py * 16 + kh) * 224 + px * 16 + kw_]);
}

__global__ __launch_bounds__(256) void assemble_kernel(const float* __restrict__ feat,
    const float* __restrict__ cls, const float* __restrict__ pos,
    const float* __restrict__ gp, float* __restrict__ x) {
  int idx = blockIdx.x * 256 + threadIdx.x;
  if (idx >= MTOK * 768) return;
  int d = idx % 768;
  int t = idx / 768;
  int s = t % 205;
  int b = t / 205;
  float v;
  if (s == 0)        v = cls[d] + pos[d];
  else if (s < 197)  v = feat[((size_t)b * 196 + (s - 1)) * 768 + d] + pos[(size_t)s * 768 + d];
  else               v = gp[(((size_t)b * 12 + 0) * 8 + (s - 197)) * 768 + d];
  x[idx] = v;
}

__global__ __launch_bounds__(256) void prompt_replace_kernel(const float* __restrict__ gp,
                                                             float* __restrict__ x, int layer) {
  int idx = blockIdx.x * 256 + threadIdx.x;
  if (idx >= B_ * 8 * 768) return;
  int d = idx % 768;
  int t = idx / 768;
  int j = t & 7, b = t >> 3;
  x[((size_t)(b * 205 + 197 + j)) * 768 + d] = gp[(((size_t)b * 12 + layer) * 8 + j) * 768 + d];
}

// ---------------------------------------------------------------- layernorm (1 wave / row, fp32)
__global__ __launch_bounds__(256) void ln_kernel(const float* __restrict__ x, int irs,
    const float* __restrict__ g, const float* __restrict__ be,
    void* __restrict__ out, int ors, int out_bf16, int nrows) {
  int row = blockIdx.x * 4 + (threadIdx.x >> 6);
  if (row >= nrows) return;
  int lane = threadIdx.x & 63;
  const float* xr = x + (size_t)row * irs;
  float v[12];
  float s = 0.f;
#pragma unroll
  for (int i = 0; i < 12; ++i) { v[i] = xr[lane + 64 * i]; s += v[i]; }
#pragma unroll
  for (int m = 1; m < 64; m <<= 1) s += __shfl_xor(s, m, 64);
  float mu = s * (1.f / 768.f);
  float ss = 0.f;
#pragma unroll
  for (int i = 0; i < 12; ++i) { float dd = v[i] - mu; ss += dd * dd; }
#pragma unroll
  for (int m = 1; m < 64; m <<= 1) ss += __shfl_xor(ss, m, 64);
  float rstd = rsqrtf(ss * (1.f / 768.f) + 1e-5f);
#pragma unroll
  for (int i = 0; i < 12; ++i) {
    int d = lane + 64 * i;
    float o = (v[i] - mu) * rstd * g[d] + be[d];
    if (out_bf16) ((bf16*)out)[(size_t)row * ors + d] = __float2bfloat16(o);
    else          ((float*)out)[(size_t)row * ors + d] = o;
  }
}

// ---------------------------------------------------------------- GEMM
// out[m,n] = act((A[m,:].W[n,:] + bias[n]) * sc) + residual
// 128x128 tile, BK=64, XOR-swizzled LDS (chunk' = chunk ^ (row&7)), supertile
// block order (G m-blocks share W-slab in L2; W tile fastest-varying).
static constexpr int SG = 8;   // m-blocks per supertile

__global__ __launch_bounds__(256) void gemm_kernel(
    const bf16* __restrict__ A, int lda,
    const bf16* __restrict__ W, int ldw,
    const float* __restrict__ bias,
    void* __restrict__ out, int ldo, int out_bf16,
    const float* __restrict__ residual, int ldr,
    int act, float scale, int scale_limit,
    int M_valid, int K, int gm, int gn) {
  __shared__ __align__(16) bf16 As[128 * 64];
  __shared__ __align__(16) bf16 Bs[128 * 64];
  const int tid = threadIdx.x;
  const int wave = tid >> 6, lane = tid & 63;
  const int quad = lane >> 4, l16 = lane & 15;

  // supertile decode: m fastest within (Gc m-blocks x gn n-blocks)
  const int bid = blockIdx.x;
  const int super = bid / (SG * gn);
  const int m_base = super * SG;
  const int Gc = min(SG, gm - m_base);
  const int rem = bid - super * (SG * gn);
  const int n_blk = rem / Gc;
  const int m_blk = m_base + (rem - n_blk * Gc);
  const int m0 = m_blk * 128, n0 = n_blk * 128;

  const int wm = (wave & 1) * 64, wn = (wave >> 1) * 64;

  // staging: per K-iter each wave issues 4 async calls per matrix;
  // call c covers rows wave*32 + c*8 + (lane>>3), swizzled source chunk.
  const int lrow = lane >> 3;                       // 0..7
  const int lcol = ((lane & 7) ^ lrow) * 8;         // swizzled element col in [0,64)
  const bf16* a_stage = A + (size_t)(m0 + wave * 32 + lrow) * lda + lcol;
  const bf16* b_stage = W + (size_t)(n0 + wave * 32 + lrow) * ldw + lcol;
  bf16* as_dst0 = As + (wave * 32 + 0) * 64;
  bf16* as_dst1 = As + (wave * 32 + 8) * 64;
  bf16* as_dst2 = As + (wave * 32 + 16) * 64;
  bf16* as_dst3 = As + (wave * 32 + 24) * 64;
  bf16* bs_dst0 = Bs + (wave * 32 + 0) * 64;
  bf16* bs_dst1 = Bs + (wave * 32 + 8) * 64;
  bf16* bs_dst2 = Bs + (wave * 32 + 16) * 64;
  bf16* bs_dst3 = Bs + (wave * 32 + 24) * 64;
  const size_t a8 = (size_t)8 * lda, b8 = (size_t)8 * ldw;

  const int sw = l16 & 7;                           // read-side swizzle

  f32x4 acc[4][4];
#pragma unroll
  for (int tm = 0; tm < 4; ++tm)
#pragma unroll
    for (int tn = 0; tn < 4; ++tn) {
      f32x4 z = {0.f, 0.f, 0.f, 0.f};
      acc[tm][tn] = z;
    }

  for (int k0 = 0; k0 < K; k0 += 64) {
    async_ld16(a_stage + k0,          as_dst0);
    async_ld16(a_stage + a8 + k0,     as_dst1);
    async_ld16(a_stage + 2*a8 + k0,   as_dst2);
    async_ld16(a_stage + 3*a8 + k0,   as_dst3);
    async_ld16(b_stage + k0,          bs_dst0);
    async_ld16(b_stage + b8 + k0,     bs_dst1);
    async_ld16(b_stage + 2*b8 + k0,   bs_dst2);
    async_ld16(b_stage + 3*b8 + k0,   bs_dst3);
    __syncthreads();

    // k-half 0: global chunks quad -> LDS chunk quad^sw
    {
      bf16x8 af[4], bfr[4];
      const int c0 = ((quad ^ sw) * 8);
#pragma unroll
      for (int tm = 0; tm < 4; ++tm)
        af[tm] = *(const bf16x8*)(As + (wm + tm * 16 + l16) * 64 + c0);
#pragma unroll
      for (int tn = 0; tn < 4; ++tn)
        bfr[tn] = *(const bf16x8*)(Bs + (wn + tn * 16 + l16) * 64 + c0);
#pragma unroll
      for (int tm = 0; tm < 4; ++tm)
#pragma unroll
        for (int tn = 0; tn < 4; ++tn)
          acc[tm][tn] = mfma16(af[tm], bfr[tn], acc[tm][tn]);
    }
    // k-half 1: global chunks quad+4
    {
      bf16x8 af[4], bfr[4];
      const int c1 = (((quad + 4) ^ sw) * 8);
#pragma unroll
      for (int tm = 0; tm < 4; ++tm)
        af[tm] = *(const bf16x8*)(As + (wm + tm * 16 + l16) * 64 + c1);
#pragma unroll
      for (int tn = 0; tn < 4; ++tn)
        bfr[tn] = *(const bf16x8*)(Bs + (wn + tn * 16 + l16) * 64 + c1);
#pragma unroll
      for (int tm = 0; tm < 4; ++tm)
#pragma unroll
        for (int tn = 0; tn < 4; ++tn)
          acc[tm][tn] = mfma16(af[tm], bfr[tn], acc[tm][tn]);
    }
    __syncthreads();
  }

#pragma unroll
  for (int tm = 0; tm < 4; ++tm) {
#pragma unroll
    for (int tn = 0; tn < 4; ++tn) {
      const int col = n0 + wn + tn * 16 + l16;
      const float bv = bias ? bias[col] : 0.f;
      const float sc = (col < scale_limit) ? scale : 1.f;
#pragma unroll
      for (int r = 0; r < 4; ++r) {
        const int row = m0 + wm + tm * 16 + quad * 4 + r;
        if (row < M_valid) {
          float v = (acc[tm][tn][r] + bv) * sc;
          if (residual) v += residual[(size_t)row * ldr + col];
          if (act) v = v / (1.f + __expf(-1.702f * v));   // QuickGELU
          if (out_bf16) ((bf16*)out)[(size_t)row * ldo + col] = __float2bfloat16(v);
          else          ((float*)out)[(size_t)row * ldo + col] = v;
        }
      }
    }
  }
}

// ---------------------------------------------------------------- fused attention (one block per (b,h))
__global__ __launch_bounds__(256) void attn_kernel(const bf16* __restrict__ qkv,
                                                   bf16* __restrict__ outb) {
  __shared__ __align__(16) bf16 Ks[208 * 72];
  __shared__ __align__(16) bf16 Vt[64 * 232];
  __shared__ __align__(16) bf16 Pc[4 * 16 * 40];
  const int h = blockIdx.x, b = blockIdx.y;
  const int tid = threadIdx.x;
  const int wave = tid >> 6, lane = tid & 63, quad = lane >> 4, l16 = lane & 15;
  const size_t rowbase = (size_t)b * 205;

  for (int idx = tid; idx < 208 * 8; idx += 256) {
    int s = idx >> 3, c = idx & 7;
    uint4 val = {0u, 0u, 0u, 0u};
    if (s < 205) val = *(const uint4*)(qkv + (rowbase + s) * 2304 + 768 + h * 64 + c * 8);
    *(uint4*)(Ks + s * 72 + c * 8) = val;
  }
  for (int idx = tid; idx < 224 * 8; idx += 256) {
    int s = idx >> 3, c = idx & 7;
    bf16 tmp[8];
    if (s < 205) {
      *(uint4*)tmp = *(const uint4*)(qkv + (rowbase + s) * 2304 + 1536 + h * 64 + c * 8);
    } else {
#pragma unroll
      for (int j = 0; j < 8; ++j) tmp[j] = __float2bfloat16(0.f);
    }
#pragma unroll
    for (int j = 0; j < 8; ++j) Vt[(c * 8 + j) * 232 + s] = tmp[j];
  }
  __syncthreads();

  bf16* Pm = Pc + wave * (16 * 40);

  for (int t = 0; t < 4; ++t) {
    const int it = t * 4 + wave;
    if (it >= 13) continue;
    const int row0 = it * 16;
    const bf16* qr = qkv + (rowbase + row0 + l16) * 2304 + h * 64;
    bf16x8 qf0 = *(const bf16x8*)(qr + quad * 8);
    bf16x8 qf1 = *(const bf16x8*)(qr + 32 + quad * 8);

    f32x4 sc[13];
#pragma unroll
    for (int nt = 0; nt < 13; ++nt) {
      f32x4 a = {0.f, 0.f, 0.f, 0.f};
      const bf16* kr = Ks + (nt * 16 + l16) * 72 + quad * 8;
      a = mfma16(qf0, *(const bf16x8*)kr, a);
      a = mfma16(qf1, *(const bf16x8*)(kr + 32), a);
      sc[nt] = a;
    }
    if (l16 >= 13) {
#pragma unroll
      for (int r = 0; r < 4; ++r) sc[12][r] = -1e30f;
    }

    float inv[4];
#pragma unroll
    for (int r = 0; r < 4; ++r) {
      float m = sc[0][r];
#pragma unroll
      for (int nt = 1; nt < 13; ++nt) m = fmaxf(m, sc[nt][r]);
      m = fmaxf(m, __shfl_xor(m, 1, 64));
      m = fmaxf(m, __shfl_xor(m, 2, 64));
      m = fmaxf(m, __shfl_xor(m, 4, 64));
      m = fmaxf(m, __shfl_xor(m, 8, 64));
      float su = 0.f;
#pragma unroll
      for (int nt = 0; nt < 13; ++nt) { float e = __expf(sc[nt][r] - m); sc[nt][r] = e; su += e; }
      su += __shfl_xor(su, 1, 64);
      su += __shfl_xor(su, 2, 64);
      su += __shfl_xor(su, 4, 64);
      su += __shfl_xor(su, 8, 64);
      inv[r] = 1.f / su;
    }

    f32x4 o0 = {0.f,0.f,0.f,0.f}, o1 = {0.f,0.f,0.f,0.f}, o2 = {0.f,0.f,0.f,0.f}, o3 = {0.f,0.f,0.f,0.f};
#pragma unroll
    for (int ks = 0; ks < 7; ++ks) {
#pragma unroll
      for (int half = 0; half < 2; ++half) {
        const int nt = ks * 2 + half;
#pragma unroll
        for (int r = 0; r < 4; ++r) {
          float pv = (nt < 13) ? sc[nt][r] * inv[r] : 0.f;
          Pm[(quad * 4 + r) * 40 + half * 16 + l16] = __float2bfloat16(pv);
        }
      }
      asm volatile("s_waitcnt lgkmcnt(0)" ::: "memory");
      bf16x8 pf = *(const bf16x8*)(Pm + l16 * 40 + quad * 8);
      const bf16* vb_ = Vt + l16 * 232 + ks * 32 + quad * 8;
      o0 = mfma16(pf, *(const bf16x8*)(vb_ + 0 * 16 * 232), o0);
      o1 = mfma16(pf, *(const bf16x8*)(vb_ + 1 * 16 * 232), o1);
      o2 = mfma16(pf, *(const bf16x8*)(vb_ + 2 * 16 * 232), o2);
      o3 = mfma16(pf, *(const bf16x8*)(vb_ + 3 * 16 * 232), o3);
      asm volatile("s_waitcnt lgkmcnt(0)" ::: "memory");
    }
#pragma unroll
    for (int r = 0; r < 4; ++r) {
      const int s = row0 + quad * 4 + r;
      if (s < 205) {
        bf16* op = outb + (rowbase + s) * 768 + h * 64 + l16;
        op[0]  = __float2bfloat16(o0[r]);
        op[16] = __float2bfloat16(o1[r]);
        op[32] = __float2bfloat16(o2[r]);
        op[48] = __float2bfloat16(o3[r]);
      }
    }
  }
}

// ---------------------------------------------------------------- launcher
extern "C" void kernel_launch(void* const* d_in, const int* in_sizes, int n_in,
                              void* d_out, int out_size, void* d_ws, size_t ws_size,
                              hipStream_t stream) {
  const float* image  = (const float*)d_in[0];
  const float* gp     = (const float*)d_in[1];
  const float* patchw = (const float*)d_in[2];
  const float* clse   = (const float*)d_in[3];
  const float* pose   = (const float*)d_in[4];
  const float* pre_g  = (const float*)d_in[5];
  const float* pre_b  = (const float*)d_in[6];
  const float* ln1_g  = (const float*)d_in[7];
  const float* ln1_b  = (const float*)d_in[8];
  const float* qw     = (const float*)d_in[9];
  const float* qb     = (const float*)d_in[10];
  const float* kw     = (const float*)d_in[11];
  const float* kb     = (const float*)d_in[12];
  const float* vw     = (const float*)d_in[13];
  const float* vb     = (const float*)d_in[14];
  const float* ow     = (const float*)d_in[15];
  const float* ob     = (const float*)d_in[16];
  const float* ln2_g  = (const float*)d_in[17];
  const float* ln2_b  = (const float*)d_in[18];
  const float* fc1w   = (const float*)d_in[19];
  const float* fc1b   = (const float*)d_in[20];
  const float* fc2w   = (const float*)d_in[21];
  const float* fc2b   = (const float*)d_in[22];
  const float* postg  = (const float*)d_in[23];
  const float* postb  = (const float*)d_in[24];

  char* ws = (char*)d_ws;
  bf16*  qkvw   = (bf16*)(ws + OFF_QKVW);
  bf16*  oww    = (bf16*)(ws + OFF_OW);
  bf16*  fc1wb  = (bf16*)(ws + OFF_FC1W);
  bf16*  fc2wb  = (bf16*)(ws + OFF_FC2W);
  bf16*  pwb    = (bf16*)(ws + OFF_PW);
  float* qkvbias= (float*)(ws + OFF_QKVB);
  float* x      = (float*)(ws + OFF_X);
  bf16*  h      = (bf16*)(ws + OFF_H);
  bf16*  qkvbuf = (bf16*)(ws + OFF_QKV);
  bf16*  ffbuf  = (bf16*)(ws + OFF_FF);
  float* feat   = (float*)(ws + OFF_FF);

  // --- weight conversion (runs every call: ws is re-poisoned) ---
  cvt_qkvw_kernel<<<20736, 256, 0, stream>>>(qw, kw, vw, qkvw);
  cvt_bf16_kernel<<<6912, 256, 0, stream>>>(ow, oww, 12 * 768 * 768 / 4);
  cvt_bf16_kernel<<<27648, 256, 0, stream>>>(fc1w, fc1wb, 12 * 3072 * 768 / 4);
  cvt_bf16_kernel<<<27648, 256, 0, stream>>>(fc2w, fc2wb, 12 * 768 * 3072 / 4);
  cvt_bf16_kernel<<<576, 256, 0, stream>>>(patchw, pwb, 768 * 768 / 4);
  cvt_qkvb_kernel<<<108, 256, 0, stream>>>(qb, kb, vb, qkvbias);

  // --- patch embedding: im2col + GEMM -> feat f32 [12544][768] ---
  im2col_kernel<<<37632, 256, 0, stream>>>(image, h);
  gemm_kernel<<<98 * 6, 256, 0, stream>>>(h, 768, pwb, 768, nullptr,
      feat, 768, 0, nullptr, 0, 0, 1.f, 0, MP_, 768, 98, 6);
  assemble_kernel<<<39360, 256, 0, stream>>>(feat, clse, pose, gp, x);
  ln_kernel<<<3280, 256, 0, stream>>>(x, 768, pre_g, pre_b, x, 768, 0, MTOK);

  for (int i = 0; i < L_; ++i) {
    if (i > 0)
      prompt_replace_kernel<<<1536, 256, 0, stream>>>(gp, x, i);
    ln_kernel<<<3280, 256, 0, stream>>>(x, 768, ln1_g + i * 768, ln1_b + i * 768, h, 768, 1, MTOK);
    gemm_kernel<<<103 * 18, 256, 0, stream>>>(h, 768,
        qkvw + (size_t)i * 2304 * 768, 768, qkvbias + i * 2304,
        qkvbuf, 2304, 1, nullptr, 0, 0, 0.125f, 768, MTOK, 768, 103, 18);
    attn_kernel<<<dim3(12, 64), 256, 0, stream>>>(qkvbuf, h);
    gemm_kernel<<<103 * 6, 256, 0, stream>>>(h, 768,
        oww + (size_t)i * 768 * 768, 768, ob + i * 768,
        x, 768, 0, x, 768, 0, 1.f, 0, MTOK, 768, 103, 6);
    ln_kernel<<<3280, 256, 0, stream>>>(x, 768, ln2_g + i * 768, ln2_b + i * 768, h, 768, 1, MTOK);
    gemm_kernel<<<103 * 24, 256, 0, stream>>>(h, 768,
        fc1wb + (size_t)i * 3072 * 768, 768, fc1b + i * 3072,
        ffbuf, 3072, 1, nullptr, 0, 1, 1.f, 0, MTOK, 768, 103, 24);
    gemm_kernel<<<103 * 6, 256, 0, stream>>>(ffbuf, 3072,
        fc2wb + (size_t)i * 768 * 3072, 3072, fc2b + i * 768,
        x, 768, 0, x, 768, 0, 1.f, 0, MTOK, 3072, 103, 6);
  }

  ln_kernel<<<16, 256, 0, stream>>>(x, 205 * 768, postg, postb, (float*)d_out, 768, 0, 64);
}